// Round 1
// baseline (993.680 us; speedup 1.0000x reference)
//
#include <hip/hip_runtime.h>
#include <math.h>

#define BATCH 16
#define ISZ   1024
#define MSZ   32768
#define DSZ   128
#define TOPK  32
#define EPSV  1e-8f

// ---------------- Kernel A: write/read projections (two GEMVs fused) ----------
// grid (128, 16), block 64. Block (d, b) computes wv[b,d], rq[b,d].
__global__ void proj_kernel(const float* __restrict__ x,
                            const float* __restrict__ Ww, const float* __restrict__ bw,
                            const float* __restrict__ Wr, const float* __restrict__ br,
                            float* __restrict__ wv, float* __restrict__ rq) {
    int d = blockIdx.x;
    int b = blockIdx.y;
    int lane = threadIdx.x;
    const float* xr  = x  + (size_t)b * ISZ;
    const float* wwr = Ww + (size_t)d * ISZ;
    const float* wrr = Wr + (size_t)d * ISZ;
    float aw = 0.f, ar = 0.f;
    for (int j = lane; j < ISZ; j += 64) {
        float xv = xr[j];
        aw = fmaf(xv, wwr[j], aw);
        ar = fmaf(xv, wrr[j], ar);
    }
    for (int off = 32; off; off >>= 1) {
        aw += __shfl_down(aw, off);
        ar += __shfl_down(ar, off);
    }
    if (lane == 0) {
        wv[b * DSZ + d] = aw + bw[d];
        rq[b * DSZ + d] = ar + br[d];
    }
}

// ---------------- Kernel B: memory row norms ---------------------------------
// one wave per row; block 256 = 4 rows/block; grid 8192.
__global__ void mnorm_kernel(const float* __restrict__ memory, float* __restrict__ mn) {
    int wave = threadIdx.x >> 6;
    int lane = threadIdx.x & 63;
    int m = blockIdx.x * 4 + wave;
    const float* row = memory + (size_t)m * DSZ;
    float a = row[lane] * row[lane] + row[lane + 64] * row[lane + 64];
    for (int off = 32; off; off >>= 1) a += __shfl_down(a, off);
    if (lane == 0) mn[m] = fmaxf(sqrtf(a), EPSV);
}

// ---------------- Kernel C: similarity + exact top-k + retrieved -------------
// one block per batch; 1024 threads; all 32768 sims live in LDS (128 KiB).
__global__ __launch_bounds__(1024)
void topk_kernel(const float* __restrict__ rq, const float* __restrict__ mn,
                 const float* __restrict__ memory, float* __restrict__ retrieved) {
    __shared__ float sim[MSZ];      // 128 KiB
    __shared__ float rq_s[DSZ];
    __shared__ float qn_s;
    __shared__ float wvv[16];
    __shared__ int   wvi[16];
    __shared__ int   topi[TOPK];

    int b = blockIdx.x;
    int tid = threadIdx.x;
    if (tid < DSZ) rq_s[tid] = rq[b * DSZ + tid];
    __syncthreads();

    // query norm (one wave)
    if (tid < 64) {
        float a = rq_s[tid] * rq_s[tid] + rq_s[tid + 64] * rq_s[tid + 64];
        for (int off = 32; off; off >>= 1) a += __shfl_down(a, off);
        if (tid == 0) qn_s = fmaxf(sqrtf(a), EPSV);
    }
    __syncthreads();
    float qn = qn_s;

    // similarities
    for (int i = tid; i < MSZ; i += 1024) {
        const float4* row = (const float4*)(memory + (size_t)i * DSZ);
        float acc = 0.f;
        #pragma unroll
        for (int j = 0; j < 32; ++j) {
            float4 v = row[j];
            acc = fmaf(v.x, rq_s[4 * j + 0], acc);
            acc = fmaf(v.y, rq_s[4 * j + 1], acc);
            acc = fmaf(v.z, rq_s[4 * j + 2], acc);
            acc = fmaf(v.w, rq_s[4 * j + 3], acc);
        }
        sim[i] = acc / (qn * mn[i]);
    }
    __syncthreads();

    // iterative argmax x 32, tie-break = smaller index (matches jax.lax.top_k)
    int lane = tid & 63, wave = tid >> 6;
    for (int k = 0; k < TOPK; ++k) {
        float bv = -INFINITY;
        int   bi = 0x7fffffff;
        for (int i = tid; i < MSZ; i += 1024) {
            float v = sim[i];
            if (v > bv) { bv = v; bi = i; }   // strided scan ascending -> keeps smaller i on tie
        }
        for (int off = 32; off; off >>= 1) {
            float ov = __shfl_down(bv, off);
            int   oi = __shfl_down(bi, off);
            if (ov > bv || (ov == bv && oi < bi)) { bv = ov; bi = oi; }
        }
        if (lane == 0) { wvv[wave] = bv; wvi[wave] = bi; }
        __syncthreads();
        if (tid == 0) {
            float fv = wvv[0]; int fi = wvi[0];
            for (int w = 1; w < 16; ++w)
                if (wvv[w] > fv || (wvv[w] == fv && wvi[w] < fi)) { fv = wvv[w]; fi = wvi[w]; }
            topi[k] = fi;
            sim[fi] = -INFINITY;
        }
        __syncthreads();
    }

    // retrieved = sum of selected rows, in selection (= descending-similarity) order
    if (tid < DSZ) {
        float s = 0.f;
        for (int k = 0; k < TOPK; ++k)
            s += memory[(size_t)topi[k] * DSZ + tid];
        retrieved[b * DSZ + tid] = s;
    }
}

// ---------------- Kernel D: output proj + write strength + update vector -----
// grid 16, block 256
__global__ void out_kernel(const float* __restrict__ retrieved, const float* __restrict__ wv,
                           const float* __restrict__ Wo, const float* __restrict__ bo,
                           float* __restrict__ out, float* __restrict__ u) {
    int b = blockIdx.x, tid = threadIdx.x;
    __shared__ float r_s[DSZ];
    __shared__ float s_sh;
    if (tid < DSZ) r_s[tid] = retrieved[b * DSZ + tid];
    __syncthreads();
    if (tid < 64) {
        float a = wv[b * DSZ + tid] * r_s[tid] + wv[b * DSZ + 64 + tid] * r_s[64 + tid];
        for (int off = 32; off; off >>= 1) a += __shfl_down(a, off);
        if (tid == 0) s_sh = 1.f / (1.f + expf(-a));
    }
    __syncthreads();
    float s = s_sh;
    if (tid < DSZ) u[b * DSZ + tid] = s * wv[b * DSZ + tid];
    for (int i = tid; i < ISZ; i += 256) {
        const float* wrow = Wo + (size_t)i * DSZ;
        float acc = 0.f;
        #pragma unroll 8
        for (int d = 0; d < DSZ; ++d) acc = fmaf(r_s[d], wrow[d], acc);
        out[b * ISZ + i] = acc + bo[i];
    }
}

// ---------------- Kernel E: new_memory = memory + u[b] broadcast -------------
// 1 float4 of memory per thread, 16 stores. grid 4096, block 256.
__global__ void bcast_kernel(const float* __restrict__ memory, const float* __restrict__ u,
                             float* __restrict__ out_nm) {
    __shared__ float4 u_s[BATCH * DSZ / 4];   // 8 KiB
    int tid = threadIdx.x;
    const float4* u4 = (const float4*)u;
    for (int i = tid; i < BATCH * DSZ / 4; i += 256) u_s[i] = u4[i];
    __syncthreads();
    size_t f = (size_t)blockIdx.x * 256 + tid;          // float4 index into memory
    float4 m4 = ((const float4*)memory)[f];
    int d4 = (int)(f & 31);                              // float4 column within row
    float4* o = (float4*)out_nm;
    #pragma unroll
    for (int b = 0; b < BATCH; ++b) {
        float4 uv = u_s[b * 32 + d4];
        float4 r = make_float4(m4.x + uv.x, m4.y + uv.y, m4.z + uv.z, m4.w + uv.w);
        o[(size_t)b * (MSZ * DSZ / 4) + f] = r;
    }
}

extern "C" void kernel_launch(void* const* d_in, const int* in_sizes, int n_in,
                              void* d_out, int out_size, void* d_ws, size_t ws_size,
                              hipStream_t stream) {
    const float* x      = (const float*)d_in[0];
    const float* memory = (const float*)d_in[1];
    const float* Ww     = (const float*)d_in[2];
    const float* bw     = (const float*)d_in[3];
    const float* Wr     = (const float*)d_in[4];
    const float* br     = (const float*)d_in[5];
    const float* Wo     = (const float*)d_in[6];
    const float* bo     = (const float*)d_in[7];

    float* out    = (float*)d_out;            // [16,1024]
    float* out_nm = out + BATCH * ISZ;        // [16,32768,128]

    float* ws        = (float*)d_ws;
    float* wv        = ws;                    // 2048
    float* rq        = ws + 2048;             // 2048
    float* mn        = ws + 4096;             // 32768
    float* retrieved = ws + 4096 + MSZ;       // 2048
    float* u         = retrieved + 2048;      // 2048

    proj_kernel<<<dim3(DSZ, BATCH), 64, 0, stream>>>(x, Ww, bw, Wr, br, wv, rq);
    mnorm_kernel<<<MSZ / 4, 256, 0, stream>>>(memory, mn);
    topk_kernel<<<BATCH, 1024, 0, stream>>>(rq, mn, memory, retrieved);
    out_kernel<<<BATCH, 256, 0, stream>>>(retrieved, wv, Wo, bo, out, u);
    bcast_kernel<<<MSZ * DSZ / 4 / 256, 256, 0, stream>>>(memory, u, out_nm);
}

// Round 2
// 163.079 us; speedup vs baseline: 6.0933x; 6.0933x over previous
//
#include <hip/hip_runtime.h>
#include <math.h>

#define BATCH 16
#define ISZ   1024
#define MSZ   32768
#define DSZ   128
#define TOPK  32
#define EPSV  1e-8f
#define NCHUNK 32              // chunks per batch for partial top-k
#define CHUNK  (MSZ / NCHUNK)  // 1024 rows per chunk
#define CPL    (CHUNK / 64)    // 16 sims per lane

// ---------------- Kernel A: write/read projections (two GEMVs fused) ----------
// grid (128, 16), block 64. Block (d, b) computes wv[b,d], rq[b,d].
__global__ void proj_kernel(const float* __restrict__ x,
                            const float* __restrict__ Ww, const float* __restrict__ bw,
                            const float* __restrict__ Wr, const float* __restrict__ br,
                            float* __restrict__ wv, float* __restrict__ rq) {
    int d = blockIdx.x;
    int b = blockIdx.y;
    int lane = threadIdx.x;
    const float* xr  = x  + (size_t)b * ISZ;
    const float* wwr = Ww + (size_t)d * ISZ;
    const float* wrr = Wr + (size_t)d * ISZ;
    float aw = 0.f, ar = 0.f;
    for (int j = lane; j < ISZ; j += 64) {
        float xv = xr[j];
        aw = fmaf(xv, wwr[j], aw);
        ar = fmaf(xv, wrr[j], ar);
    }
    for (int off = 32; off; off >>= 1) {
        aw += __shfl_down(aw, off);
        ar += __shfl_down(ar, off);
    }
    if (lane == 0) {
        wv[b * DSZ + d] = aw + bw[d];
        rq[b * DSZ + d] = ar + br[d];
    }
}

// ---------------- Kernel B: memory row norms ---------------------------------
__global__ void mnorm_kernel(const float* __restrict__ memory, float* __restrict__ mn) {
    int wave = threadIdx.x >> 6;
    int lane = threadIdx.x & 63;
    int m = blockIdx.x * 4 + wave;
    const float* row = memory + (size_t)m * DSZ;
    float a = row[lane] * row[lane] + row[lane + 64] * row[lane + 64];
    for (int off = 32; off; off >>= 1) a += __shfl_down(a, off);
    if (lane == 0) mn[m] = fmaxf(sqrtf(a), EPSV);
}

// ---------------- Kernel C: similarities, rows read once ---------------------
// grid 256 blocks x 128 threads; thread = one memory row, computes 16 dots.
__global__ __launch_bounds__(128)
void sim_kernel(const float* __restrict__ rq, const float* __restrict__ mn,
                const float* __restrict__ memory, float* __restrict__ sim) {
    __shared__ float qn_s[BATCH];
    int tid = threadIdx.x;
    // query norms (redundant per block, trivial): thread t -> b=t>>3, seg=t&7
    {
        int b = tid >> 3, seg = tid & 7;
        float a = 0.f;
        #pragma unroll
        for (int j = 0; j < 16; ++j) {
            float v = rq[b * DSZ + seg * 16 + j];
            a = fmaf(v, v, a);
        }
        for (int off = 4; off; off >>= 1) a += __shfl_down(a, off, 8);
        if (seg == 0) qn_s[b] = fmaxf(sqrtf(a), EPSV);
    }
    __syncthreads();

    int r = blockIdx.x * 128 + tid;
    const float4* row = (const float4*)(memory + (size_t)r * DSZ);
    const float4* rq4 = (const float4*)rq;   // uniform indices -> scalar loads
    float acc[BATCH];
    #pragma unroll
    for (int b = 0; b < BATCH; ++b) acc[b] = 0.f;
    float mnr = mn[r];
    #pragma unroll 4
    for (int j = 0; j < 32; ++j) {
        float4 v = row[j];
        #pragma unroll
        for (int b = 0; b < BATCH; ++b) {
            float4 q = rq4[b * 32 + j];
            acc[b] = fmaf(v.x, q.x, fmaf(v.y, q.y, fmaf(v.z, q.z, fmaf(v.w, q.w, acc[b]))));
        }
    }
    #pragma unroll
    for (int b = 0; b < BATCH; ++b)
        sim[(size_t)b * MSZ + r] = acc[b] / (qn_s[b] * mnr);
}

// ---------------- Kernel D: per-wave partial top-32 over 1024-row chunks -----
// 512 wave-tasks (16 batches x 32 chunks); block 256 = 4 waves; grid 128.
// Exact jax.lax.top_k semantics: (value desc, index asc) total order.
__global__ __launch_bounds__(256)
void ptopk_kernel(const float* __restrict__ sim,
                  float* __restrict__ cand_v, int* __restrict__ cand_i) {
    int lane = threadIdx.x & 63;
    int task = blockIdx.x * 4 + (threadIdx.x >> 6);
    int b     = task >> 5;     // NCHUNK = 32
    int chunk = task & 31;
    int base  = chunk * CHUNK;
    const float* s = sim + (size_t)b * MSZ + base;

    float val[CPL];
    #pragma unroll
    for (int i = 0; i < CPL; ++i) val[i] = s[i * 64 + lane];

    // local running max; index base+i*64+lane is monotone in i, so strict '>'
    // keeps the smaller global index on ties.
    float lv = -INFINITY; int lm = -1;
    #pragma unroll
    for (int i = 0; i < CPL; ++i) if (val[i] > lv) { lv = val[i]; lm = i; }

    float keep_v = -INFINITY; int keep_i = 0x7FFFFFFF;
    for (int k = 0; k < TOPK; ++k) {
        float bv = lv;
        int   bi = (lm < 0) ? 0x7FFFFFFF : base + lm * 64 + lane;
        #pragma unroll
        for (int off = 32; off; off >>= 1) {
            float ov = __shfl_xor(bv, off);
            int   oi = __shfl_xor(bi, off);
            if (ov > bv || (ov == bv && oi < bi)) { bv = ov; bi = oi; }
        }
        if (lane == k) { keep_v = bv; keep_i = bi; }
        int rel = bi - base;
        if (rel >= 0 && (rel & 63) == lane && (rel >> 6) < CPL) {
            val[rel >> 6] = -INFINITY;
            lv = -INFINITY; lm = -1;
            #pragma unroll
            for (int i = 0; i < CPL; ++i) if (val[i] > lv) { lv = val[i]; lm = i; }
        }
    }
    if (lane < TOPK) {
        cand_v[task * TOPK + lane] = keep_v;
        cand_i[task * TOPK + lane] = keep_i;
    }
}

// ---------------- Kernel E: merge candidates -> exact top-32; retrieved; u ---
// grid 16 (one block per batch), block 128.
__global__ __launch_bounds__(128)
void merge_kernel(const float* __restrict__ cand_v, const int* __restrict__ cand_i,
                  const float* __restrict__ memory, const float* __restrict__ wv,
                  float* __restrict__ retrieved, float* __restrict__ u) {
    __shared__ int   topi[TOPK];
    __shared__ float r_s[DSZ];
    __shared__ float s_sh;
    int b = blockIdx.x;
    int tid = threadIdx.x;
    int lane = tid & 63;
    const int NC = NCHUNK * TOPK;   // 1024 candidates per batch
    const int PL = NC / 64;         // 16 per lane

    if (tid < 64) {
        float val[PL]; int idx[PL];
        #pragma unroll
        for (int i = 0; i < PL; ++i) {
            val[i] = cand_v[b * NC + i * 64 + lane];
            idx[i] = cand_i[b * NC + i * 64 + lane];
        }
        float lv; int li, lm;
        {
            lv = -INFINITY; li = 0x7FFFFFFF; lm = -1;
            #pragma unroll
            for (int i = 0; i < PL; ++i)
                if (val[i] > lv || (val[i] == lv && idx[i] < li)) { lv = val[i]; li = idx[i]; lm = i; }
        }
        float keep_v = -INFINITY; int keep_i = 0x7FFFFFFF;
        for (int k = 0; k < TOPK; ++k) {
            float bv = lv; int bi = li;
            #pragma unroll
            for (int off = 32; off; off >>= 1) {
                float ov = __shfl_xor(bv, off);
                int   oi = __shfl_xor(bi, off);
                if (ov > bv || (ov == bv && oi < bi)) { bv = ov; bi = oi; }
            }
            if (lane == k) { keep_v = bv; keep_i = bi; }
            if (bi == li && lm >= 0) {   // candidate indices are globally unique
                val[lm] = -INFINITY;
                lv = -INFINITY; li = 0x7FFFFFFF; lm = -1;
                #pragma unroll
                for (int i = 0; i < PL; ++i)
                    if (val[i] > lv || (val[i] == lv && idx[i] < li)) { lv = val[i]; li = idx[i]; lm = i; }
            }
        }
        if (lane < TOPK) topi[lane] = keep_i;
    }
    __syncthreads();

    // retrieved = sum of selected rows in selection (descending-sim) order
    float rsum = 0.f;
    for (int k = 0; k < TOPK; ++k)
        rsum += memory[(size_t)topi[k] * DSZ + tid];
    r_s[tid] = rsum;
    retrieved[b * DSZ + tid] = rsum;
    __syncthreads();

    if (tid < 64) {
        float a = wv[b * DSZ + tid] * r_s[tid] + wv[b * DSZ + 64 + tid] * r_s[64 + tid];
        for (int off = 32; off; off >>= 1) a += __shfl_down(a, off);
        if (tid == 0) s_sh = 1.f / (1.f + expf(-a));
    }
    __syncthreads();
    u[b * DSZ + tid] = s_sh * wv[b * DSZ + tid];
}

// ---------------- Kernel F: output projection --------------------------------
// grid (8, 16), block 128; thread computes one output element.
__global__ __launch_bounds__(128)
void out_kernel(const float* __restrict__ retrieved, const float* __restrict__ Wo,
                const float* __restrict__ bo, float* __restrict__ out) {
    __shared__ float r_s[DSZ];
    int b = blockIdx.y;
    int i = blockIdx.x * 128 + threadIdx.x;
    r_s[threadIdx.x] = retrieved[b * DSZ + threadIdx.x];
    __syncthreads();
    const float4* w4 = (const float4*)(Wo + (size_t)i * DSZ);
    const float4* r4 = (const float4*)r_s;
    float acc = 0.f;
    #pragma unroll 8
    for (int j = 0; j < 32; ++j) {
        float4 w = w4[j];
        float4 r = r4[j];
        acc = fmaf(w.x, r.x, fmaf(w.y, r.y, fmaf(w.z, r.z, fmaf(w.w, r.w, acc))));
    }
    out[b * ISZ + i] = acc + bo[i];
}

// ---------------- Kernel G: new_memory = memory + u[b] broadcast -------------
__global__ void bcast_kernel(const float* __restrict__ memory, const float* __restrict__ u,
                             float* __restrict__ out_nm) {
    __shared__ float4 u_s[BATCH * DSZ / 4];   // 8 KiB
    int tid = threadIdx.x;
    const float4* u4 = (const float4*)u;
    for (int i = tid; i < BATCH * DSZ / 4; i += 256) u_s[i] = u4[i];
    __syncthreads();
    size_t f = (size_t)blockIdx.x * 256 + tid;          // float4 index into memory
    float4 m4 = ((const float4*)memory)[f];
    int d4 = (int)(f & 31);                              // float4 column within row
    float4* o = (float4*)out_nm;
    #pragma unroll
    for (int b = 0; b < BATCH; ++b) {
        float4 uv = u_s[b * 32 + d4];
        float4 r = make_float4(m4.x + uv.x, m4.y + uv.y, m4.z + uv.z, m4.w + uv.w);
        o[(size_t)b * (MSZ * DSZ / 4) + f] = r;
    }
}

extern "C" void kernel_launch(void* const* d_in, const int* in_sizes, int n_in,
                              void* d_out, int out_size, void* d_ws, size_t ws_size,
                              hipStream_t stream) {
    const float* x      = (const float*)d_in[0];
    const float* memory = (const float*)d_in[1];
    const float* Ww     = (const float*)d_in[2];
    const float* bw     = (const float*)d_in[3];
    const float* Wr     = (const float*)d_in[4];
    const float* br     = (const float*)d_in[5];
    const float* Wo     = (const float*)d_in[6];
    const float* bo     = (const float*)d_in[7];

    float* out    = (float*)d_out;            // [16,1024]
    float* out_nm = out + BATCH * ISZ;        // [16,32768,128]

    float* ws        = (float*)d_ws;
    float* wv        = ws;                           // 2048
    float* rq        = wv + BATCH * DSZ;             // 2048
    float* mn        = rq + BATCH * DSZ;             // 32768
    float* sim       = mn + MSZ;                     // 16*32768 = 524288
    float* cand_v    = sim + (size_t)BATCH * MSZ;    // 16*1024 = 16384
    int*   cand_i    = (int*)(cand_v + BATCH * NCHUNK * TOPK);  // 16384
    float* retrieved = (float*)(cand_i + BATCH * NCHUNK * TOPK);// 2048
    float* u         = retrieved + BATCH * DSZ;      // 2048

    proj_kernel<<<dim3(DSZ, BATCH), 64, 0, stream>>>(x, Ww, bw, Wr, br, wv, rq);
    mnorm_kernel<<<MSZ / 4, 256, 0, stream>>>(memory, mn);
    sim_kernel<<<MSZ / 128, 128, 0, stream>>>(rq, mn, memory, sim);
    ptopk_kernel<<<(BATCH * NCHUNK) / 4, 256, 0, stream>>>(sim, cand_v, cand_i);
    merge_kernel<<<BATCH, 128, 0, stream>>>(cand_v, cand_i, memory, wv, retrieved, u);
    out_kernel<<<dim3(8, BATCH), 128, 0, stream>>>(retrieved, Wo, bo, out);
    bcast_kernel<<<MSZ * DSZ / 4 / 256, 256, 0, stream>>>(memory, u, out_nm);
}